// Round 1
// baseline (92.233 us; speedup 1.0000x reference)
//
#include <hip/hip_runtime.h>

// IWT3: x [B, 8*C, D, H, W] f32 -> out [B, C, 2D, 2H, 2W] f32
// B=2, C=32, D=H=W=48. Pure memory-bound butterfly; each input element read
// once, each output element written once, all 16B-vectorized.

#define B_ 2
#define C_ 32
#define D_ 48
#define H_ 48
#define W_ 48

__global__ __launch_bounds__(256) void iwt3_kernel(
    const float* __restrict__ x, float* __restrict__ out)
{
    constexpr unsigned WQ = W_ / 4;                          // 12 float4 per row
    constexpr unsigned NT = B_ * 2u * C_ * D_ * H_ * WQ;     // 3,538,944 threads

    unsigned idx = blockIdx.x * 256u + threadIdx.x;
    if (idx >= NT) return;

    // decompose: [b][d0][c][d][h][wq]
    unsigned wq = idx % WQ;  unsigned t = idx / WQ;
    unsigned h  = t % H_;    t /= H_;
    unsigned d  = t % D_;    t /= D_;
    unsigned c  = t % C_;    t /= C_;
    unsigned d0 = t & 1u;
    unsigned b  = t >> 1;

    const size_t gstride = (size_t)C_ * D_ * H_ * W_;        // per-group stride
    size_t in_off = ((((size_t)b * 8 + 4u * d0) * C_ + c) * D_ + d) * ((size_t)H_ * W_)
                  + (size_t)h * W_ + (size_t)wq * 4;

    const float4 v1 = *(const float4*)(x + in_off);
    const float4 v2 = *(const float4*)(x + in_off + gstride);
    const float4 v3 = *(const float4*)(x + in_off + 2 * gstride);
    const float4 v4 = *(const float4*)(x + in_off + 3 * gstride);

    const float a1[4] = {v1.x, v1.y, v1.z, v1.w};
    const float a2[4] = {v2.x, v2.y, v2.z, v2.w};
    const float a3[4] = {v3.x, v3.y, v3.z, v3.w};
    const float a4[4] = {v4.x, v4.y, v4.z, v4.w};

    // a_{d0,h0,w0} = 0.5*(g1 + s2*g2 + s3*g3 + s2*s3*g4), s2=+1 iff w0, s3=+1 iff h0
    float r0[8], r1[8];
#pragma unroll
    for (int k = 0; k < 4; ++k) {
        const float p = a1[k], q = a2[k], r = a3[k], s = a4[k];
        r0[2*k]   = 0.5f * (p - q - r + s);   // h0=0, w0=0
        r0[2*k+1] = 0.5f * (p + q - r - s);   // h0=0, w0=1
        r1[2*k]   = 0.5f * (p - q + r - s);   // h0=1, w0=0
        r1[2*k+1] = 0.5f * (p + q + r + s);   // h0=1, w0=1
    }

    // out[b, c, 2d+d0, 2h+h0, 2w+w0]; one thread owns both h0 rows, 8 w-elems
    size_t orow = (((size_t)(b * C_ + c) * (2 * D_) + (2u * d + d0)) * (2 * H_) + 2u * h)
                    * (2 * W_)
                + (size_t)wq * 8;
    *(float4*)(out + orow)              = make_float4(r0[0], r0[1], r0[2], r0[3]);
    *(float4*)(out + orow + 4)          = make_float4(r0[4], r0[5], r0[6], r0[7]);
    *(float4*)(out + orow + 2 * W_)     = make_float4(r1[0], r1[1], r1[2], r1[3]);
    *(float4*)(out + orow + 2 * W_ + 4) = make_float4(r1[4], r1[5], r1[6], r1[7]);
}

extern "C" void kernel_launch(void* const* d_in, const int* in_sizes, int n_in,
                              void* d_out, int out_size, void* d_ws, size_t ws_size,
                              hipStream_t stream) {
    const float* x = (const float*)d_in[0];
    float* out = (float*)d_out;

    constexpr unsigned NT = B_ * 2u * C_ * D_ * H_ * (W_ / 4);
    constexpr unsigned BLOCK = 256;
    constexpr unsigned GRID = (NT + BLOCK - 1) / BLOCK;      // 13824 blocks

    iwt3_kernel<<<GRID, BLOCK, 0, stream>>>(x, out);
}

// Round 2
// 73.317 us; speedup vs baseline: 1.2580x; 1.2580x over previous
//
#include <hip/hip_runtime.h>

// IWT3: x [B, 8*C, D, H, W] f32 -> out [B, C, 2D, 2H, 2W] f32
// B=2, C=32, D=H=W=48.
// Output-centric mapping: every global_store_dwordx4 is a fully dense,
// contiguous 1024B wave write. Inputs read as float2 per group; the h0
// row-pair duplicates coalesce in L1/L2 (same wave), so HBM fetch stays ~1x.

#define B_ 2
#define C_ 32
#define D_ 48
#define H_ 48
#define W_ 48

typedef float vf4 __attribute__((ext_vector_type(4)));

__global__ __launch_bounds__(256) void iwt3_kernel(
    const float* __restrict__ x, float* __restrict__ out)
{
    // thread space: [b][c][dlo(48)][hout(96)][m(24)], 2 chunks per thread
    // (dout = dlo and dlo+48). Total = 2*32*48*96*24 = 7,077,888 threads.
    unsigned tid = blockIdx.x * 256u + threadIdx.x;

    unsigned m    = tid % 24u;  unsigned t = tid / 24u;
    unsigned hout = t % 96u;    t /= 96u;
    unsigned dlo  = t % 48u;    t /= 48u;
    unsigned c    = t % 32u;
    unsigned b    = t / 32u;

    unsigned h   = hout >> 1;
    unsigned h0  = hout & 1u;
    unsigned d0  = dlo & 1u;          // (dlo+48) has the same parity
    unsigned din = dlo >> 1;          // chunk2 uses din + 24

    const size_t gs = (size_t)C_ * D_ * H_ * W_;        // per-group stride
    const size_t plane = (size_t)H_ * W_;               // 2304
    size_t base = ((size_t)(b * 8u + 4u * d0) * C_ + c) * ((size_t)D_ * plane)
                + (size_t)din * plane + (size_t)h * W_ + 2u * m;

    const float s3 = h0 ? 1.0f : -1.0f;   // sign of g3/g4 contribution

    vf4 r1, r2;
    {
        float2 g1 = *(const float2*)(x + base);
        float2 g2 = *(const float2*)(x + base + gs);
        float2 g3 = *(const float2*)(x + base + 2 * gs);
        float2 g4 = *(const float2*)(x + base + 3 * gs);
        float e0 = fmaf(s3, g3.x, g1.x), f0 = fmaf(s3, g4.x, g2.x);
        float e1 = fmaf(s3, g3.y, g1.y), f1 = fmaf(s3, g4.y, g2.y);
        r1 = (vf4){0.5f * (e0 - f0), 0.5f * (e0 + f0),
                   0.5f * (e1 - f1), 0.5f * (e1 + f1)};
    }
    {
        size_t b2 = base + (size_t)24 * plane;
        float2 g1 = *(const float2*)(x + b2);
        float2 g2 = *(const float2*)(x + b2 + gs);
        float2 g3 = *(const float2*)(x + b2 + 2 * gs);
        float2 g4 = *(const float2*)(x + b2 + 3 * gs);
        float e0 = fmaf(s3, g3.x, g1.x), f0 = fmaf(s3, g4.x, g2.x);
        float e1 = fmaf(s3, g3.y, g1.y), f1 = fmaf(s3, g4.y, g2.y);
        r2 = (vf4){0.5f * (e0 - f0), 0.5f * (e0 + f0),
                   0.5f * (e1 - f1), 0.5f * (e1 + f1)};
    }

    // out flat: [b][c][dout(96)][hout(96)][wout(96)]
    size_t o1 = ((size_t)(b * C_ + c) * 96u + dlo) * 9216u
              + (size_t)hout * 96u + 4u * m;
    size_t o2 = o1 + (size_t)48 * 9216u;

    __builtin_nontemporal_store(r1, (vf4*)(out + o1));
    __builtin_nontemporal_store(r2, (vf4*)(out + o2));
}

extern "C" void kernel_launch(void* const* d_in, const int* in_sizes, int n_in,
                              void* d_out, int out_size, void* d_ws, size_t ws_size,
                              hipStream_t stream) {
    const float* x = (const float*)d_in[0];
    float* out = (float*)d_out;

    constexpr unsigned NT = B_ * C_ * 48u * 96u * 24u;   // 7,077,888
    constexpr unsigned BLOCK = 256;
    constexpr unsigned GRID = NT / BLOCK;                // 27,648 exact

    iwt3_kernel<<<GRID, BLOCK, 0, stream>>>(x, out);
}